// Round 1
// baseline (512.808 us; speedup 1.0000x reference)
//
#include <hip/hip_runtime.h>

typedef unsigned short u16;
typedef __attribute__((ext_vector_type(8))) short bf16x8;
typedef __attribute__((ext_vector_type(4))) float f32x4;
typedef __attribute__((ext_vector_type(4))) unsigned short us4;

#define DEV static __device__ __forceinline__

DEV u16 bf_trunc(float x){ return (u16)(__builtin_bit_cast(unsigned int, x) >> 16); }
DEV float bf_tof(u16 h){ unsigned int u = ((unsigned int)h) << 16; return __builtin_bit_cast(float, u); }
DEV u16 bf_rne(float x){
    unsigned int u = __builtin_bit_cast(unsigned int, x);
    return (u16)((u + 0x7fffu + ((u >> 16) & 1u)) >> 16);
}

// XOR swizzle on 16B column-blocks: element (row r, col k) of a 64-col bf16 tile
// lives at r*64 + SW(r, k>>3) + (k&7).  Keeps wave64 ds_read_b128 at the 8-phase floor.
#define SW(r,cb) ((((cb) ^ ((r)&7)))*8)

// ---------------- split fp32 -> hi/lo bf16 ----------------
__global__ __launch_bounds__(256) void k_split(const float4* __restrict__ in,
                                               u16* __restrict__ hi, u16* __restrict__ lo, int n4){
    int i = blockIdx.x*256 + threadIdx.x;
    if (i >= n4) return;
    float4 v = in[i];
    float vv[4] = {v.x, v.y, v.z, v.w};
    us4 h, l;
    #pragma unroll
    for (int j = 0; j < 4; ++j){
        u16 hs = bf_trunc(vv[j]);
        h[j] = hs;
        l[j] = bf_trunc(vv[j] - bf_tof(hs));
    }
    ((us4*)hi)[i] = h;
    ((us4*)lo)[i] = l;
}

// ---------------- qkv GEMM (split bf16, 3-MFMA) ----------------
// C[m][o] = sum_c x[m][c]*W[o][c], M=8192, O=2304, K=768.
// grid: x = 36 (o-tiles of 64), y = 64 (m-tiles of 128). 256 threads, 4 waves of 64x32.
__global__ __launch_bounds__(256) void k_qkv(const u16* __restrict__ xh, const u16* __restrict__ xl,
                                             const u16* __restrict__ wh, const u16* __restrict__ wl,
                                             u16* __restrict__ qh, u16* __restrict__ ql,
                                             u16* __restrict__ kh, u16* __restrict__ kl,
                                             u16* __restrict__ vh){
    __shared__ u16 Ah[128*64], Al[128*64], Bh[64*64], Bl[64*64];
    const int tid = threadIdx.x, lane = tid & 63, wid = tid >> 6;
    const int lm = lane & 15, lg = lane >> 4;
    const int n0 = blockIdx.x * 64, m0 = blockIdx.y * 128;
    const int wm = (wid >> 1) * 64, wn = (wid & 1) * 32;
    f32x4 acc[4][2];
    const f32x4 z = {0.f, 0.f, 0.f, 0.f};
    #pragma unroll
    for (int i = 0; i < 4; ++i) for (int j = 0; j < 2; ++j) acc[i][j] = z;

    for (int kp = 0; kp < 12; ++kp){
        const int kb = kp * 64;
        #pragma unroll
        for (int c = tid; c < 1024; c += 256){
            int r = c >> 3, cb = c & 7;
            *(bf16x8*)(Ah + r*64 + SW(r,cb)) = *(const bf16x8*)(xh + (size_t)(m0+r)*768 + kb + cb*8);
            *(bf16x8*)(Al + r*64 + SW(r,cb)) = *(const bf16x8*)(xl + (size_t)(m0+r)*768 + kb + cb*8);
        }
        #pragma unroll
        for (int c = tid; c < 512; c += 256){
            int r = c >> 3, cb = c & 7;
            *(bf16x8*)(Bh + r*64 + SW(r,cb)) = *(const bf16x8*)(wh + (size_t)(n0+r)*768 + kb + cb*8);
            *(bf16x8*)(Bl + r*64 + SW(r,cb)) = *(const bf16x8*)(wl + (size_t)(n0+r)*768 + kb + cb*8);
        }
        __syncthreads();
        #pragma unroll
        for (int ks = 0; ks < 2; ++ks){
            bf16x8 a_h[4], a_l[4], b_h[2], b_l[2];
            #pragma unroll
            for (int mt = 0; mt < 4; ++mt){
                int r = wm + mt*16 + lm, cb = lg + 4*ks;
                a_h[mt] = *(const bf16x8*)(Ah + r*64 + SW(r,cb));
                a_l[mt] = *(const bf16x8*)(Al + r*64 + SW(r,cb));
            }
            #pragma unroll
            for (int nt = 0; nt < 2; ++nt){
                int r = wn + nt*16 + lm, cb = lg + 4*ks;
                b_h[nt] = *(const bf16x8*)(Bh + r*64 + SW(r,cb));
                b_l[nt] = *(const bf16x8*)(Bl + r*64 + SW(r,cb));
            }
            #pragma unroll
            for (int mt = 0; mt < 4; ++mt)
            #pragma unroll
            for (int nt = 0; nt < 2; ++nt){
                acc[mt][nt] = __builtin_amdgcn_mfma_f32_16x16x32_bf16(a_h[mt], b_h[nt], acc[mt][nt], 0,0,0);
                acc[mt][nt] = __builtin_amdgcn_mfma_f32_16x16x32_bf16(a_h[mt], b_l[nt], acc[mt][nt], 0,0,0);
                acc[mt][nt] = __builtin_amdgcn_mfma_f32_16x16x32_bf16(a_l[mt], b_h[nt], acc[mt][nt], 0,0,0);
            }
        }
        __syncthreads();
    }
    // epilogue: scatter into q/k/v [B][H][N][D]; o-tile maps to a single (t, head)
    const int t = n0 / 768;
    const int h = (n0 % 768) / 64;
    #pragma unroll
    for (int mt = 0; mt < 4; ++mt)
    #pragma unroll
    for (int nt = 0; nt < 2; ++nt)
    #pragma unroll
    for (int rr = 0; rr < 4; ++rr){
        int grow = m0 + wm + mt*16 + lg*4 + rr;      // bn
        int d    = wn + nt*16 + lm;                   // 0..63
        int b = grow >> 11, n = grow & 2047;
        size_t off = ((size_t)((b*12 + h)*2048 + n))*64 + d;
        float v = acc[mt][nt][rr];
        if (t == 0){ u16 hs = bf_trunc(v); qh[off] = hs; ql[off] = bf_trunc(v - bf_tof(hs)); }
        else if (t == 1){ u16 hs = bf_trunc(v); kh[off] = hs; kl[off] = bf_trunc(v - bf_tof(hs)); }
        else { vh[off] = bf_rne(v); }
    }
}

// ---------------- flash attention ----------------
// grid: x = 32 (q-tiles of 64), y = 48 (b*12+h). 256 threads; wave w owns q-rows [w*16, w*16+16).
__global__ __launch_bounds__(256) void k_attn(const u16* __restrict__ qh, const u16* __restrict__ ql,
                                              const u16* __restrict__ kh, const u16* __restrict__ kl,
                                              const u16* __restrict__ vh, u16* __restrict__ x1h){
    __shared__ u16 Kh[64*64], Kl[64*64], Vt[64*64], Pl[4][16*64];
    const int tid = threadIdx.x, lane = tid & 63, wid = tid >> 6;
    const int lm = lane & 15, lg = lane >> 4;
    const size_t bh_base = (size_t)blockIdx.y * 2048 * 64;
    const int q0 = blockIdx.x * 64;

    bf16x8 qfh[2], qfl[2];
    {
        int qrow = q0 + wid*16 + lm;
        const u16* qp  = qh + bh_base + (size_t)qrow*64;
        const u16* qlp = ql + bh_base + (size_t)qrow*64;
        #pragma unroll
        for (int ks = 0; ks < 2; ++ks){
            qfh[ks] = *(const bf16x8*)(qp  + lg*8 + ks*32);
            qfl[ks] = *(const bf16x8*)(qlp + lg*8 + ks*32);
        }
    }
    f32x4 o_acc[4];
    const f32x4 z = {0.f,0.f,0.f,0.f};
    #pragma unroll
    for (int i = 0; i < 4; ++i) o_acc[i] = z;
    float m_run[4], l_run[4];
    #pragma unroll
    for (int i = 0; i < 4; ++i){ m_run[i] = -INFINITY; l_run[i] = 0.f; }

    for (int kt = 0; kt < 32; ++kt){
        const u16* kp_ = kh + bh_base + (size_t)kt*4096;
        const u16* klp = kl + bh_base + (size_t)kt*4096;
        const u16* vp  = vh + bh_base + (size_t)kt*4096;
        #pragma unroll
        for (int c = tid; c < 512; c += 256){
            int r = c >> 3, cb = c & 7;
            *(bf16x8*)(Kh + r*64 + SW(r,cb)) = *(const bf16x8*)(kp_ + r*64 + cb*8);
            *(bf16x8*)(Kl + r*64 + SW(r,cb)) = *(const bf16x8*)(klp + r*64 + cb*8);
        }
        #pragma unroll
        for (int c = tid; c < 512; c += 256){
            int kk = c >> 3, d0 = (c & 7)*8;
            bf16x8 vv = *(const bf16x8*)(vp + kk*64 + d0);
            #pragma unroll
            for (int j = 0; j < 8; ++j){
                int d = d0 + j;
                Vt[d*64 + SW(d, kk>>3) + (kk&7)] = (u16)vv[j];
            }
        }
        __syncthreads();
        // S = Q K^T  (split 3-MFMA), 16x64 per wave
        f32x4 s[4];
        #pragma unroll
        for (int i = 0; i < 4; ++i) s[i] = z;
        #pragma unroll
        for (int ks = 0; ks < 2; ++ks){
            #pragma unroll
            for (int nt = 0; nt < 4; ++nt){
                int r = nt*16 + lm, cb = lg + 4*ks;
                bf16x8 bh_ = *(const bf16x8*)(Kh + r*64 + SW(r,cb));
                bf16x8 bl_ = *(const bf16x8*)(Kl + r*64 + SW(r,cb));
                s[nt] = __builtin_amdgcn_mfma_f32_16x16x32_bf16(qfh[ks], bh_, s[nt], 0,0,0);
                s[nt] = __builtin_amdgcn_mfma_f32_16x16x32_bf16(qfh[ks], bl_, s[nt], 0,0,0);
                s[nt] = __builtin_amdgcn_mfma_f32_16x16x32_bf16(qfl[ks], bh_, s[nt], 0,0,0);
            }
        }
        // online softmax (scores *= 8)
        float pv[4][4];
        #pragma unroll
        for (int rr = 0; rr < 4; ++rr){
            float rmax = -INFINITY;
            #pragma unroll
            for (int nt = 0; nt < 4; ++nt) rmax = fmaxf(rmax, s[nt][rr]);
            rmax *= 8.0f;
            #pragma unroll
            for (int mm = 1; mm < 16; mm <<= 1) rmax = fmaxf(rmax, __shfl_xor(rmax, mm, 64));
            float mnew = fmaxf(m_run[rr], rmax);
            float corr = __expf(m_run[rr] - mnew);
            float rsum = 0.f;
            #pragma unroll
            for (int nt = 0; nt < 4; ++nt){
                float p = __expf(s[nt][rr]*8.0f - mnew);
                pv[nt][rr] = p; rsum += p;
            }
            #pragma unroll
            for (int mm = 1; mm < 16; mm <<= 1) rsum += __shfl_xor(rsum, mm, 64);
            l_run[rr] = l_run[rr]*corr + rsum;
            m_run[rr] = mnew;
            #pragma unroll
            for (int dt = 0; dt < 4; ++dt) o_acc[dt][rr] *= corr;
        }
        // stage P (own wave region, in-wave RAW handled by compiler waitcnt)
        u16* P = Pl[wid];
        #pragma unroll
        for (int nt = 0; nt < 4; ++nt)
        #pragma unroll
        for (int rr = 0; rr < 4; ++rr){
            int r = lg*4 + rr, col = nt*16 + lm;
            P[r*64 + SW(r, col>>3) + (col&7)] = bf_rne(pv[nt][rr]);
        }
        // O += P V
        #pragma unroll
        for (int ks = 0; ks < 2; ++ks){
            int cb = lg + 4*ks;
            bf16x8 pa = *(const bf16x8*)(P + lm*64 + SW(lm,cb));
            #pragma unroll
            for (int dt = 0; dt < 4; ++dt){
                int vr = dt*16 + lm;
                bf16x8 vb = *(const bf16x8*)(Vt + vr*64 + SW(vr,cb));
                o_acc[dt] = __builtin_amdgcn_mfma_f32_16x16x32_bf16(pa, vb, o_acc[dt], 0,0,0);
            }
        }
        __syncthreads();
    }
    const int b = blockIdx.y / 12, hh = blockIdx.y % 12;
    #pragma unroll
    for (int dt = 0; dt < 4; ++dt)
    #pragma unroll
    for (int rr = 0; rr < 4; ++rr){
        int qrow = q0 + wid*16 + lg*4 + rr;
        int cc = hh*64 + dt*16 + lm;
        float o = o_acc[dt][rr] / l_run[rr];
        x1h[((size_t)(b*2048 + qrow))*768 + cc] = bf_rne(o);
    }
}

// ---------------- proj GEMM + bias + residual ----------------
// grid: x = 12, y = 64
__global__ __launch_bounds__(256) void k_proj(const u16* __restrict__ x1h, const u16* __restrict__ pwh,
                                              const float* __restrict__ pb, const float* __restrict__ xres,
                                              float* __restrict__ out){
    __shared__ u16 Ah[128*64], Bh[64*64];
    const int tid = threadIdx.x, lane = tid & 63, wid = tid >> 6;
    const int lm = lane & 15, lg = lane >> 4;
    const int n0 = blockIdx.x * 64, m0 = blockIdx.y * 128;
    const int wm = (wid >> 1) * 64, wn = (wid & 1) * 32;
    f32x4 acc[4][2];
    const f32x4 z = {0.f,0.f,0.f,0.f};
    #pragma unroll
    for (int i = 0; i < 4; ++i) for (int j = 0; j < 2; ++j) acc[i][j] = z;

    for (int kp = 0; kp < 12; ++kp){
        const int kb = kp * 64;
        #pragma unroll
        for (int c = tid; c < 1024; c += 256){
            int r = c >> 3, cb = c & 7;
            *(bf16x8*)(Ah + r*64 + SW(r,cb)) = *(const bf16x8*)(x1h + (size_t)(m0+r)*768 + kb + cb*8);
        }
        #pragma unroll
        for (int c = tid; c < 512; c += 256){
            int r = c >> 3, cb = c & 7;
            *(bf16x8*)(Bh + r*64 + SW(r,cb)) = *(const bf16x8*)(pwh + (size_t)(n0+r)*768 + kb + cb*8);
        }
        __syncthreads();
        #pragma unroll
        for (int ks = 0; ks < 2; ++ks){
            bf16x8 af[4], bfr[2];
            #pragma unroll
            for (int mt = 0; mt < 4; ++mt){
                int r = wm + mt*16 + lm, cb = lg + 4*ks;
                af[mt] = *(const bf16x8*)(Ah + r*64 + SW(r,cb));
            }
            #pragma unroll
            for (int nt = 0; nt < 2; ++nt){
                int r = wn + nt*16 + lm, cb = lg + 4*ks;
                bfr[nt] = *(const bf16x8*)(Bh + r*64 + SW(r,cb));
            }
            #pragma unroll
            for (int mt = 0; mt < 4; ++mt)
            #pragma unroll
            for (int nt = 0; nt < 2; ++nt)
                acc[mt][nt] = __builtin_amdgcn_mfma_f32_16x16x32_bf16(af[mt], bfr[nt], acc[mt][nt], 0,0,0);
        }
        __syncthreads();
    }
    #pragma unroll
    for (int mt = 0; mt < 4; ++mt)
    #pragma unroll
    for (int nt = 0; nt < 2; ++nt)
    #pragma unroll
    for (int rr = 0; rr < 4; ++rr){
        int grow = m0 + wm + mt*16 + lg*4 + rr;
        int gcol = n0 + wn + nt*16 + lm;
        size_t o = (size_t)grow*768 + gcol;
        out[o] = acc[mt][nt][rr] + pb[gcol] + xres[o];
    }
}

// ---------------- LayerNorm (in-place on out) ----------------
__global__ __launch_bounds__(256) void k_ln(float* __restrict__ out, const float* __restrict__ gamma,
                                            const float* __restrict__ beta){
    const int tid = threadIdx.x, lane = tid & 63, wid = tid >> 6;
    float* p = out + (size_t)blockIdx.x * 768;
    float v[3], s = 0.f, s2 = 0.f;
    #pragma unroll
    for (int j = 0; j < 3; ++j){ v[j] = p[tid + j*256]; s += v[j]; s2 += v[j]*v[j]; }
    #pragma unroll
    for (int mm = 1; mm < 64; mm <<= 1){ s += __shfl_xor(s, mm, 64); s2 += __shfl_xor(s2, mm, 64); }
    __shared__ float red[8];
    if (lane == 0){ red[wid] = s; red[4 + wid] = s2; }
    __syncthreads();
    s  = red[0] + red[1] + red[2] + red[3];
    s2 = red[4] + red[5] + red[6] + red[7];
    const float mu  = s * (1.0f/768.0f);
    const float var = s2 * (1.0f/768.0f) - mu*mu;
    const float inv = rsqrtf(var + 1e-5f);
    #pragma unroll
    for (int j = 0; j < 3; ++j){
        int c = tid + j*256;
        p[c] = (v[j] - mu) * inv * gamma[c] + beta[c];
    }
}

extern "C" void kernel_launch(void* const* d_in, const int* in_sizes, int n_in,
                              void* d_out, int out_size, void* d_ws, size_t ws_size,
                              hipStream_t stream){
    const float* x      = (const float*)d_in[0];
    const float* qkv_w  = (const float*)d_in[1];
    const float* proj_w = (const float*)d_in[2];
    const float* pb     = (const float*)d_in[3];
    const float* gamma  = (const float*)d_in[4];
    const float* beta   = (const float*)d_in[5];
    float* out = (float*)d_out;

    constexpr size_t SZ_X   = 8192ull * 768;    // 6291456
    constexpr size_t SZ_W   = 2304ull * 768;    // 1769472
    constexpr size_t SZ_PW  = 768ull * 768;     // 589824
    constexpr size_t SZ_QKV = 48ull * 2048 * 64;// 6291456
    constexpr size_t TOTAL  = 2*SZ_X + 2*SZ_W + 2*SZ_PW + 5*SZ_QKV + SZ_X;
    if (ws_size < TOTAL * sizeof(u16)) return;  // visible failure (absmax = ref max) if ws too small

    u16* ws  = (u16*)d_ws;
    u16* xh  = ws;
    u16* xl  = xh  + SZ_X;
    u16* wh  = xl  + SZ_X;
    u16* wl  = wh  + SZ_W;
    u16* pwh = wl  + SZ_W;
    u16* pwl = pwh + SZ_PW;
    u16* qh  = pwl + SZ_PW;
    u16* ql  = qh  + SZ_QKV;
    u16* kh  = ql  + SZ_QKV;
    u16* kl  = kh  + SZ_QKV;
    u16* vh  = kl  + SZ_QKV;
    u16* x1h = vh  + SZ_QKV;

    k_split<<<(SZ_X/4  + 255)/256, 256, 0, stream>>>((const float4*)x,      xh,  xl,  SZ_X/4);
    k_split<<<(SZ_W/4  + 255)/256, 256, 0, stream>>>((const float4*)qkv_w,  wh,  wl,  SZ_W/4);
    k_split<<<(SZ_PW/4 + 255)/256, 256, 0, stream>>>((const float4*)proj_w, pwh, pwl, SZ_PW/4);
    k_qkv <<<dim3(36, 64), 256, 0, stream>>>(xh, xl, wh, wl, qh, ql, kh, kl, vh);
    k_attn<<<dim3(32, 48), 256, 0, stream>>>(qh, ql, kh, kl, vh, x1h);
    k_proj<<<dim3(12, 64), 256, 0, stream>>>(x1h, pwh, pb, x, out);
    k_ln  <<<8192, 256, 0, stream>>>(out, gamma, beta);
}

// Round 2
// 388.620 us; speedup vs baseline: 1.3196x; 1.3196x over previous
//
#include <hip/hip_runtime.h>

typedef unsigned short u16;
typedef __attribute__((ext_vector_type(8))) short bf16x8;
typedef __attribute__((ext_vector_type(8))) _Float16 f16x8;
typedef __attribute__((ext_vector_type(4))) float f32x4;
typedef __attribute__((ext_vector_type(4))) unsigned short us4;
typedef __attribute__((ext_vector_type(4))) unsigned int u32x4;

#define DEV static __device__ __forceinline__

DEV u16 bf_trunc(float x){ return (u16)(__builtin_bit_cast(unsigned int, x) >> 16); }
DEV float bf_tof(u16 h){ unsigned int u = ((unsigned int)h) << 16; return __builtin_bit_cast(float, u); }
DEV u16 bf_rne(float x){
    unsigned int u = __builtin_bit_cast(unsigned int, x);
    return (u16)((u + 0x7fffu + ((u >> 16) & 1u)) >> 16);
}
DEV u16 f16_rne(float x){ _Float16 h = (_Float16)x; return __builtin_bit_cast(unsigned short, h); }

// XOR swizzle on 16B column-blocks of a 64-col u16 tile: (r, col-chunk cb) -> r*64 + SW(r,cb)
#define SW(r,cb) ((((cb) ^ ((r)&7)))*8)

// ---------------- split fp32 -> hi/lo bf16 ----------------
__global__ __launch_bounds__(256) void k_split(const float4* __restrict__ in,
                                               u16* __restrict__ hi, u16* __restrict__ lo, int n4){
    int i = blockIdx.x*256 + threadIdx.x;
    if (i >= n4) return;
    float4 v = in[i];
    float vv[4] = {v.x, v.y, v.z, v.w};
    us4 h, l;
    #pragma unroll
    for (int j = 0; j < 4; ++j){
        u16 hs = bf_trunc(vv[j]);
        h[j] = hs;
        l[j] = bf_trunc(vv[j] - bf_tof(hs));
    }
    ((us4*)hi)[i] = h;
    ((us4*)lo)[i] = l;
}

// ---------------- qkv GEMM (split bf16, 3-MFMA) ----------------
// C[m][o] = sum_c x[m][c]*W[o][c], M=8192, O=2304, K=768.
// Outputs: q,k as fp16 [B,H,N,D]; v as bf16 TRANSPOSED [B,H,D,N].
__global__ __launch_bounds__(256) void k_qkv(const u16* __restrict__ xh, const u16* __restrict__ xl,
                                             const u16* __restrict__ wh, const u16* __restrict__ wl,
                                             u16* __restrict__ qf, u16* __restrict__ kf,
                                             u16* __restrict__ vt){
    __shared__ u16 Ah[128*64], Al[128*64], Bh[64*64], Bl[64*64];
    const int tid = threadIdx.x, lane = tid & 63, wid = tid >> 6;
    const int lm = lane & 15, lg = lane >> 4;
    const int n0 = blockIdx.x * 64, m0 = blockIdx.y * 128;
    const int wm = (wid >> 1) * 64, wn = (wid & 1) * 32;
    f32x4 acc[4][2];
    const f32x4 z = {0.f, 0.f, 0.f, 0.f};
    #pragma unroll
    for (int i = 0; i < 4; ++i) for (int j = 0; j < 2; ++j) acc[i][j] = z;

    for (int kp = 0; kp < 12; ++kp){
        const int kb = kp * 64;
        #pragma unroll
        for (int c = tid; c < 1024; c += 256){
            int r = c >> 3, cb = c & 7;
            *(bf16x8*)(Ah + r*64 + SW(r,cb)) = *(const bf16x8*)(xh + (size_t)(m0+r)*768 + kb + cb*8);
            *(bf16x8*)(Al + r*64 + SW(r,cb)) = *(const bf16x8*)(xl + (size_t)(m0+r)*768 + kb + cb*8);
        }
        #pragma unroll
        for (int c = tid; c < 512; c += 256){
            int r = c >> 3, cb = c & 7;
            *(bf16x8*)(Bh + r*64 + SW(r,cb)) = *(const bf16x8*)(wh + (size_t)(n0+r)*768 + kb + cb*8);
            *(bf16x8*)(Bl + r*64 + SW(r,cb)) = *(const bf16x8*)(wl + (size_t)(n0+r)*768 + kb + cb*8);
        }
        __syncthreads();
        #pragma unroll
        for (int ks = 0; ks < 2; ++ks){
            bf16x8 a_h[4], a_l[4], b_h[2], b_l[2];
            #pragma unroll
            for (int mt = 0; mt < 4; ++mt){
                int r = wm + mt*16 + lm, cb = lg + 4*ks;
                a_h[mt] = *(const bf16x8*)(Ah + r*64 + SW(r,cb));
                a_l[mt] = *(const bf16x8*)(Al + r*64 + SW(r,cb));
            }
            #pragma unroll
            for (int nt = 0; nt < 2; ++nt){
                int r = wn + nt*16 + lm, cb = lg + 4*ks;
                b_h[nt] = *(const bf16x8*)(Bh + r*64 + SW(r,cb));
                b_l[nt] = *(const bf16x8*)(Bl + r*64 + SW(r,cb));
            }
            #pragma unroll
            for (int mt = 0; mt < 4; ++mt)
            #pragma unroll
            for (int nt = 0; nt < 2; ++nt){
                acc[mt][nt] = __builtin_amdgcn_mfma_f32_16x16x32_bf16(a_h[mt], b_h[nt], acc[mt][nt], 0,0,0);
                acc[mt][nt] = __builtin_amdgcn_mfma_f32_16x16x32_bf16(a_h[mt], b_l[nt], acc[mt][nt], 0,0,0);
                acc[mt][nt] = __builtin_amdgcn_mfma_f32_16x16x32_bf16(a_l[mt], b_h[nt], acc[mt][nt], 0,0,0);
            }
        }
        __syncthreads();
    }
    const int t = n0 / 768;
    const int h = (n0 % 768) / 64;
    #pragma unroll
    for (int mt = 0; mt < 4; ++mt)
    #pragma unroll
    for (int nt = 0; nt < 2; ++nt)
    #pragma unroll
    for (int rr = 0; rr < 4; ++rr){
        int grow = m0 + wm + mt*16 + lg*4 + rr;      // bn
        int d    = wn + nt*16 + lm;                   // 0..63
        int b = grow >> 11, n = grow & 2047;
        float v = acc[mt][nt][rr];
        if (t == 0)      qf[((size_t)((b*12 + h)*2048 + n))*64 + d] = f16_rne(v);
        else if (t == 1) kf[((size_t)((b*12 + h)*2048 + n))*64 + d] = f16_rne(v);
        else             vt[((size_t)((b*12 + h)*64 + d))*2048 + n] = bf_rne(v);
    }
}

// ---------------- flash attention (swapped QK^T, in-register P) ----------------
// grid: x = 32 (q-tiles of 64), y = 48 (b*12+h). 4 waves; wave w owns q-rows [w*16, w*16+16).
// Per lane: q = lane&15, lg = lane>>4 holds S^T rows kk = nt*16 + lg*4 + rr.
__global__ __launch_bounds__(256) void k_attn(const u16* __restrict__ qf, const u16* __restrict__ kf,
                                              const u16* __restrict__ vt, u16* __restrict__ x1h){
    __shared__ u16 Kf[64*64], Vs[64*64];
    const int tid = threadIdx.x, lane = tid & 63, wid = tid >> 6;
    const int lm = lane & 15, lg = lane >> 4;
    const size_t bh_base = (size_t)blockIdx.y * 2048 * 64;   // same element count for vt
    const int q0 = blockIdx.x * 64;

    // Q as B-fragment (fp16), d = lg*8 + ks*32 + j
    f16x8 qb[2];
    {
        const u16* qp = qf + bh_base + (size_t)(q0 + wid*16 + lm)*64;
        qb[0] = *(const f16x8*)(qp + lg*8);
        qb[1] = *(const f16x8*)(qp + lg*8 + 32);
    }
    f32x4 o_acc[4];
    const f32x4 z = {0.f,0.f,0.f,0.f};
    #pragma unroll
    for (int i = 0; i < 4; ++i) o_acc[i] = z;
    float m_run = -INFINITY, l_run = 0.f;

    const int srcA = ((lg & 1) * 2) * 16 + lm;   // source lane for A-frag low quad
    const int srcB = srcA + 16;                  // high quad
    const int hi_sel = lg >> 1;

    for (int kt = 0; kt < 32; ++kt){
        const u16* kp = kf + bh_base + (size_t)kt*4096;
        const u16* vp = vt + bh_base + (size_t)kt*64;
        #pragma unroll
        for (int c = tid; c < 512; c += 256){
            int r = c >> 3, cb = c & 7;
            *(bf16x8*)(Kf + r*64 + SW(r,cb)) = *(const bf16x8*)(kp + r*64 + cb*8);
            *(bf16x8*)(Vs + r*64 + SW(r,cb)) = *(const bf16x8*)(vp + (size_t)r*2048 + cb*8);
        }
        __syncthreads();

        // S^T = K·Q^T : D[row=kk within nt*16][col=q=lm]
        f32x4 st[4];
        #pragma unroll
        for (int i = 0; i < 4; ++i) st[i] = z;
        #pragma unroll
        for (int ks = 0; ks < 2; ++ks){
            #pragma unroll
            for (int nt = 0; nt < 4; ++nt){
                int r = nt*16 + lm, cb = lg + 4*ks;
                f16x8 ka = *(const f16x8*)(Kf + r*64 + SW(r,cb));
                st[nt] = __builtin_amdgcn_mfma_f32_16x16x32_f16(ka, qb[ks], st[nt], 0,0,0);
            }
        }
        // per-lane softmax over this lane's 16 kk values (scores *= 8)
        float sc[16];
        #pragma unroll
        for (int nt = 0; nt < 4; ++nt)
        #pragma unroll
        for (int rr = 0; rr < 4; ++rr) sc[nt*4+rr] = st[nt][rr] * 8.0f;
        float lmax = sc[0];
        #pragma unroll
        for (int i = 1; i < 16; ++i) lmax = fmaxf(lmax, sc[i]);
        lmax = fmaxf(lmax, __shfl_xor(lmax, 16, 64));
        lmax = fmaxf(lmax, __shfl_xor(lmax, 32, 64));
        float mnew = fmaxf(m_run, lmax);
        float corr = __expf(m_run - mnew);
        float p[16], rsum = 0.f;
        #pragma unroll
        for (int i = 0; i < 16; ++i){ p[i] = __expf(sc[i] - mnew); rsum += p[i]; }
        rsum += __shfl_xor(rsum, 16, 64);
        rsum += __shfl_xor(rsum, 32, 64);
        l_run = l_run * corr + rsum;
        m_run = mnew;
        // rescale O (corr for q-row lg*4+rr lives at lane lm = lg*4+rr)
        #pragma unroll
        for (int rr = 0; rr < 4; ++rr){
            float cq = __shfl(corr, (lane & 48) | (lg*4 + rr), 64);
            #pragma unroll
            for (int dt = 0; dt < 4; ++dt) o_acc[dt][rr] *= cq;
        }
        // pack P to bf16 pairs: pk[nt][h] = (rr=2h, rr=2h+1)
        unsigned int pk[4][2];
        #pragma unroll
        for (int nt = 0; nt < 4; ++nt)
        #pragma unroll
        for (int h = 0; h < 2; ++h)
            pk[nt][h] = (unsigned int)bf_rne(p[nt*4 + 2*h]) |
                        ((unsigned int)bf_rne(p[nt*4 + 2*h + 1]) << 16);
        // O += P·V : A-frag for ks has kk = ks*32 + lg*8 + j, assembled via shfl
        #pragma unroll
        for (int ks = 0; ks < 2; ++ks){
            unsigned int w0a = __shfl(pk[ks*2][0],   srcA, 64);
            unsigned int w0b = __shfl(pk[ks*2+1][0], srcA, 64);
            unsigned int w1a = __shfl(pk[ks*2][1],   srcA, 64);
            unsigned int w1b = __shfl(pk[ks*2+1][1], srcA, 64);
            unsigned int w2a = __shfl(pk[ks*2][0],   srcB, 64);
            unsigned int w2b = __shfl(pk[ks*2+1][0], srcB, 64);
            unsigned int w3a = __shfl(pk[ks*2][1],   srcB, 64);
            unsigned int w3b = __shfl(pk[ks*2+1][1], srcB, 64);
            u32x4 wv;
            wv[0] = hi_sel ? w0b : w0a;
            wv[1] = hi_sel ? w1b : w1a;
            wv[2] = hi_sel ? w2b : w2a;
            wv[3] = hi_sel ? w3b : w3a;
            bf16x8 pa = __builtin_bit_cast(bf16x8, wv);
            #pragma unroll
            for (int dt = 0; dt < 4; ++dt){
                int r = dt*16 + lm, cb = lg + 4*ks;
                bf16x8 vb = *(const bf16x8*)(Vs + r*64 + SW(r,cb));
                o_acc[dt] = __builtin_amdgcn_mfma_f32_16x16x32_bf16(pa, vb, o_acc[dt], 0,0,0);
            }
        }
        __syncthreads();
    }
    const int b = blockIdx.y / 12, hh = blockIdx.y % 12;
    #pragma unroll
    for (int rr = 0; rr < 4; ++rr){
        float lr = __shfl(l_run, (lane & 48) | (lg*4 + rr), 64);
        float linv = 1.0f / lr;
        int qrow = q0 + wid*16 + lg*4 + rr;
        #pragma unroll
        for (int dt = 0; dt < 4; ++dt){
            int cc = hh*64 + dt*16 + lm;
            x1h[((size_t)(b*2048 + qrow))*768 + cc] = bf_rne(o_acc[dt][rr] * linv);
        }
    }
}

// ---------------- proj GEMM + bias + residual ----------------
__global__ __launch_bounds__(256) void k_proj(const u16* __restrict__ x1h, const u16* __restrict__ pwh,
                                              const float* __restrict__ pb, const float* __restrict__ xres,
                                              float* __restrict__ out){
    __shared__ u16 Ah[128*64], Bh[64*64];
    const int tid = threadIdx.x, lane = tid & 63, wid = tid >> 6;
    const int lm = lane & 15, lg = lane >> 4;
    const int n0 = blockIdx.x * 64, m0 = blockIdx.y * 128;
    const int wm = (wid >> 1) * 64, wn = (wid & 1) * 32;
    f32x4 acc[4][2];
    const f32x4 z = {0.f,0.f,0.f,0.f};
    #pragma unroll
    for (int i = 0; i < 4; ++i) for (int j = 0; j < 2; ++j) acc[i][j] = z;

    for (int kp = 0; kp < 12; ++kp){
        const int kb = kp * 64;
        #pragma unroll
        for (int c = tid; c < 1024; c += 256){
            int r = c >> 3, cb = c & 7;
            *(bf16x8*)(Ah + r*64 + SW(r,cb)) = *(const bf16x8*)(x1h + (size_t)(m0+r)*768 + kb + cb*8);
        }
        #pragma unroll
        for (int c = tid; c < 512; c += 256){
            int r = c >> 3, cb = c & 7;
            *(bf16x8*)(Bh + r*64 + SW(r,cb)) = *(const bf16x8*)(pwh + (size_t)(n0+r)*768 + kb + cb*8);
        }
        __syncthreads();
        #pragma unroll
        for (int ks = 0; ks < 2; ++ks){
            bf16x8 af[4], bfr[2];
            #pragma unroll
            for (int mt = 0; mt < 4; ++mt){
                int r = wm + mt*16 + lm, cb = lg + 4*ks;
                af[mt] = *(const bf16x8*)(Ah + r*64 + SW(r,cb));
            }
            #pragma unroll
            for (int nt = 0; nt < 2; ++nt){
                int r = wn + nt*16 + lm, cb = lg + 4*ks;
                bfr[nt] = *(const bf16x8*)(Bh + r*64 + SW(r,cb));
            }
            #pragma unroll
            for (int mt = 0; mt < 4; ++mt)
            #pragma unroll
            for (int nt = 0; nt < 2; ++nt)
                acc[mt][nt] = __builtin_amdgcn_mfma_f32_16x16x32_bf16(af[mt], bfr[nt], acc[mt][nt], 0,0,0);
        }
        __syncthreads();
    }
    #pragma unroll
    for (int mt = 0; mt < 4; ++mt)
    #pragma unroll
    for (int nt = 0; nt < 2; ++nt)
    #pragma unroll
    for (int rr = 0; rr < 4; ++rr){
        int grow = m0 + wm + mt*16 + lg*4 + rr;
        int gcol = n0 + wn + nt*16 + lm;
        size_t o = (size_t)grow*768 + gcol;
        out[o] = acc[mt][nt][rr] + pb[gcol] + xres[o];
    }
}

// ---------------- LayerNorm (in-place on out) ----------------
__global__ __launch_bounds__(256) void k_ln(float* __restrict__ out, const float* __restrict__ gamma,
                                            const float* __restrict__ beta){
    const int tid = threadIdx.x, lane = tid & 63, wid = tid >> 6;
    float* p = out + (size_t)blockIdx.x * 768;
    float v[3], s = 0.f, s2 = 0.f;
    #pragma unroll
    for (int j = 0; j < 3; ++j){ v[j] = p[tid + j*256]; s += v[j]; s2 += v[j]*v[j]; }
    #pragma unroll
    for (int mm = 1; mm < 64; mm <<= 1){ s += __shfl_xor(s, mm, 64); s2 += __shfl_xor(s2, mm, 64); }
    __shared__ float red[8];
    if (lane == 0){ red[wid] = s; red[4 + wid] = s2; }
    __syncthreads();
    s  = red[0] + red[1] + red[2] + red[3];
    s2 = red[4] + red[5] + red[6] + red[7];
    const float mu  = s * (1.0f/768.0f);
    const float var = s2 * (1.0f/768.0f) - mu*mu;
    const float inv = rsqrtf(var + 1e-5f);
    #pragma unroll
    for (int j = 0; j < 3; ++j){
        int c = tid + j*256;
        p[c] = (v[j] - mu) * inv * gamma[c] + beta[c];
    }
}

extern "C" void kernel_launch(void* const* d_in, const int* in_sizes, int n_in,
                              void* d_out, int out_size, void* d_ws, size_t ws_size,
                              hipStream_t stream){
    const float* x      = (const float*)d_in[0];
    const float* qkv_w  = (const float*)d_in[1];
    const float* proj_w = (const float*)d_in[2];
    const float* pb     = (const float*)d_in[3];
    const float* gamma  = (const float*)d_in[4];
    const float* beta   = (const float*)d_in[5];
    float* out = (float*)d_out;

    constexpr size_t SZ_X   = 8192ull * 768;    // 6291456 (== per-tensor q/k/v/x1 size)
    constexpr size_t SZ_W   = 2304ull * 768;
    constexpr size_t SZ_PW  = 768ull * 768;
    constexpr size_t TOTAL  = 6*SZ_X + 2*SZ_W + 2*SZ_PW;
    if (ws_size < TOTAL * sizeof(u16)) return;

    u16* ws  = (u16*)d_ws;
    u16* xh  = ws;
    u16* xl  = xh  + SZ_X;
    u16* wh  = xl  + SZ_X;
    u16* wl  = wh  + SZ_W;
    u16* pwh = wl  + SZ_W;
    u16* pwl = pwh + SZ_PW;
    u16* qf  = pwl + SZ_PW;
    u16* kf  = qf  + SZ_X;
    u16* vt  = kf  + SZ_X;
    u16* x1h = vt  + SZ_X;

    k_split<<<(SZ_X/4  + 255)/256, 256, 0, stream>>>((const float4*)x,      xh,  xl,  SZ_X/4);
    k_split<<<(SZ_W/4  + 255)/256, 256, 0, stream>>>((const float4*)qkv_w,  wh,  wl,  SZ_W/4);
    k_split<<<(SZ_PW/4 + 255)/256, 256, 0, stream>>>((const float4*)proj_w, pwh, pwl, SZ_PW/4);
    k_qkv <<<dim3(36, 64), 256, 0, stream>>>(xh, xl, wh, wl, qf, kf, vt);
    k_attn<<<dim3(32, 48), 256, 0, stream>>>(qf, kf, vt, x1h);
    k_proj<<<dim3(12, 64), 256, 0, stream>>>(x1h, pwh, pb, x, out);
    k_ln  <<<8192, 256, 0, stream>>>(out, gamma, beta);
}